// Round 9
// baseline (369.252 us; speedup 1.0000x reference)
//
#include <hip/hip_runtime.h>
#include <stdint.h>

typedef __attribute__((ext_vector_type(8))) short bf16x8;
typedef __attribute__((ext_vector_type(4))) short bf16x4;
typedef __attribute__((ext_vector_type(4))) float f32x4;
typedef __attribute__((ext_vector_type(4))) unsigned u32x4;
typedef __attribute__((ext_vector_type(2))) unsigned u32x2;

#define S_LEN 2048
#define HIDDEN 2048
#define N_HEADS 32
#define N_KV 8
#define HEAD_DIM 64
#define KVD (N_KV * HEAD_DIM)   // 512

__device__ __forceinline__ float bf2f(short u) {
  return __builtin_bit_cast(float, ((unsigned)(unsigned short)u) << 16);
}
__device__ __forceinline__ short f2bf(float f) {
  unsigned u = __builtin_bit_cast(unsigned, f);
  u += 0x7FFFu + ((u >> 16) & 1u);
  return (short)(u >> 16);
}
__device__ __forceinline__ unsigned cvtpk(float lo, float hi) {
  unsigned r;
  asm("v_cvt_pk_bf16_f32 %0, %1, %2" : "=v"(r) : "v"(lo), "v"(hi));
  return r;
}
__device__ __forceinline__ bf16x8 cvt8(f32x4 lo, f32x4 hi) {
  bf16x8 r;
#pragma unroll
  for (int j = 0; j < 4; ++j) { r[j] = f2bf(lo[j]); r[j + 4] = f2bf(hi[j]); }
  return r;
}
__device__ __forceinline__ void storeC(float* p, float v) { *p = v; }
__device__ __forceinline__ void storeC(short* p, float v) { *p = f2bf(v); }

__device__ __forceinline__ void gll16(const void* g, void* l) {
  __builtin_amdgcn_global_load_lds(
      (const __attribute__((address_space(1))) void*)g,
      (__attribute__((address_space(3))) void*)l, 16, 0, 0);
}

// ---------------------------------------------------------------------------
// fp32 -> bf16 bulk convert, 5 segments, grid-stride, float4 units.
// ---------------------------------------------------------------------------
struct CvtArgs {
  const float* src[5];
  short* dst[5];
  int cnt4[5];
};
__global__ void cvt_bf16(CvtArgs a, int total4) {
  int u = blockIdx.x * 256 + threadIdx.x;
  const int stride = gridDim.x * 256;
  for (; u < total4; u += stride) {
    int s = 0, off = u;
    while (off >= a.cnt4[s]) { off -= a.cnt4[s]; ++s; }
    f32x4 v = *(const f32x4*)(a.src[s] + (size_t)off * 4);
    bf16x4 r;
#pragma unroll
    for (int j = 0; j < 4; ++j) r[j] = f2bf(v[j]);
    *(bf16x4*)(a.dst[s] + (size_t)off * 4) = r;
  }
}

// ---------------------------------------------------------------------------
// FAST GEMM (m97 structure): C[M,N] = A[M,K] @ W[N,K]^T, bf16 in, bf16/fp32 out.
// 128x128 tile, BK=32, global_load_lds width=16 staging, linear LDS.
// (XCD swizzle tried R7: delta was run noise, reverted — keep simple.)
// ---------------------------------------------------------------------------
template <typename CT>
__launch_bounds__(256, 3)
__global__ void gemm_lds(const short* __restrict__ A, const short* __restrict__ W,
                         CT* __restrict__ C, int M, int N, int K) {
  __shared__ short As[128 * 32];
  __shared__ short Ws[128 * 32];
  const int tid  = threadIdx.x;
  const int lane = tid & 63;
  const int w    = tid >> 6;
  const int wm = w >> 1, wn = w & 1;
  const int lr = lane & 15, lg = lane >> 4;
  const int m0 = blockIdx.y * 128, n0 = blockIdx.x * 128;

  const size_t a0 = (size_t)(m0 + w * 16 + (lane >> 2)) * K + (lane & 3) * 8;
  const size_t a1 = a0 + (size_t)64 * K;
  const size_t b0 = (size_t)(n0 + w * 16 + (lane >> 2)) * K + (lane & 3) * 8;
  const size_t b1 = b0 + (size_t)64 * K;
  short* lA0 = &As[(w * 16) * 32];
  short* lA1 = &As[(64 + w * 16) * 32];
  short* lB0 = &Ws[(w * 16) * 32];
  short* lB1 = &Ws[(64 + w * 16) * 32];

  f32x4 acc[4][4] = {};

  for (int k0 = 0; k0 < K; k0 += 32) {
    __syncthreads();
    gll16(A + a0 + k0, lA0);
    gll16(A + a1 + k0, lA1);
    gll16(W + b0 + k0, lB0);
    gll16(W + b1 + k0, lB1);
    __syncthreads();
    bf16x8 af[4], bfr[4];
#pragma unroll
    for (int i = 0; i < 4; ++i) {
      af[i]  = *(const bf16x8*)&As[(wm * 64 + i * 16 + lr) * 32 + lg * 8];
      bfr[i] = *(const bf16x8*)&Ws[(wn * 64 + i * 16 + lr) * 32 + lg * 8];
    }
#pragma unroll
    for (int i = 0; i < 4; ++i)
#pragma unroll
      for (int j = 0; j < 4; ++j)
        acc[i][j] = __builtin_amdgcn_mfma_f32_16x16x32_bf16(af[i], bfr[j], acc[i][j], 0, 0, 0);
  }

#pragma unroll
  for (int i = 0; i < 4; ++i)
#pragma unroll
    for (int j = 0; j < 4; ++j) {
      const int row = m0 + wm * 64 + i * 16 + lg * 4;
      const int col = n0 + wn * 64 + j * 16 + lr;
#pragma unroll
      for (int r = 0; r < 4; ++r)
        storeC(&C[(size_t)(row + r) * N + col], acc[i][j][r]);
    }
}

// ---------------------------------------------------------------------------
// FALLBACK GEMM (register-staged, converts fp32 in flight).
// ---------------------------------------------------------------------------
template <typename AT, typename CT>
__launch_bounds__(256, 2)
__global__ void gemm_bt(const AT* __restrict__ A, const float* __restrict__ W,
                        CT* __restrict__ C, int M, int N, int K) {
  __shared__ short As[128][40];
  __shared__ short Ws[128][40];
  const int tid  = threadIdx.x;
  const int lane = tid & 63;
  const int wid  = tid >> 6;
  const int wm = wid >> 1, wn = wid & 1;
  const int lr = lane & 15, lg = lane >> 4;
  const int m0 = blockIdx.y * 128, n0 = blockIdx.x * 128;
  const int srow = tid >> 2;
  const int scol = (tid & 3) * 8;

  f32x4 acc[4][4] = {};
  const AT*    Ap = A + (size_t)(m0 + srow) * K + scol;
  const float* Wp = W + (size_t)(n0 + srow) * K + scol;

  for (int k0 = 0; k0 < K; k0 += 32) {
    bf16x8 a0, a1, b0, b1;
    if constexpr (sizeof(AT) == 4) {
      a0 = cvt8(*(const f32x4*)(Ap + k0), *(const f32x4*)(Ap + k0 + 4));
      a1 = cvt8(*(const f32x4*)(Ap + (size_t)64 * K + k0),
                *(const f32x4*)(Ap + (size_t)64 * K + k0 + 4));
    } else {
      a0 = *(const bf16x8*)(Ap + k0);
      a1 = *(const bf16x8*)(Ap + (size_t)64 * K + k0);
    }
    b0 = cvt8(*(const f32x4*)(Wp + k0), *(const f32x4*)(Wp + k0 + 4));
    b1 = cvt8(*(const f32x4*)(Wp + (size_t)64 * K + k0),
              *(const f32x4*)(Wp + (size_t)64 * K + k0 + 4));
    __syncthreads();
    *(bf16x8*)&As[srow][scol]      = a0;
    *(bf16x8*)&As[srow + 64][scol] = a1;
    *(bf16x8*)&Ws[srow][scol]      = b0;
    *(bf16x8*)&Ws[srow + 64][scol] = b1;
    __syncthreads();
    bf16x8 af[4], bfr[4];
#pragma unroll
    for (int i = 0; i < 4; ++i) {
      af[i]  = *(const bf16x8*)&As[wm * 64 + i * 16 + lr][lg * 8];
      bfr[i] = *(const bf16x8*)&Ws[wn * 64 + i * 16 + lr][lg * 8];
    }
#pragma unroll
    for (int i = 0; i < 4; ++i)
#pragma unroll
      for (int j = 0; j < 4; ++j)
        acc[i][j] = __builtin_amdgcn_mfma_f32_16x16x32_bf16(af[i], bfr[j], acc[i][j], 0, 0, 0);
  }
#pragma unroll
  for (int i = 0; i < 4; ++i)
#pragma unroll
    for (int j = 0; j < 4; ++j) {
      const int row = m0 + wm * 64 + i * 16 + lg * 4;
      const int col = n0 + wn * 64 + j * 16 + lr;
#pragma unroll
      for (int r = 0; r < 4; ++r)
        storeC(&C[(size_t)(row + r) * N + col], acc[i][j][r]);
    }
}

// ---------------------------------------------------------------------------
// RoPE, head h -> cols 64h..64h+63 of a [rows, rowstride] bf16 buffer.
// ---------------------------------------------------------------------------
template <int NH>
__global__ void rope_kernel(short* __restrict__ buf, int rowstride, int total) {
  int idx = blockIdx.x * 256 + threadIdx.x;
  if (idx >= total) return;
  const int i   = idx & 31;
  const int hh  = (idx >> 5) % NH;
  const int row = (idx >> 5) / NH;
  const int pos = row & (S_LEN - 1);
  const float invf = exp2f(-(float)i * (13.287712379549449f / 32.0f));
  const float ang  = (float)pos * invf;
  float sn, c;
  sincosf(ang, &sn, &c);
  size_t base = (size_t)row * rowstride + hh * 64;
  float x1 = bf2f(buf[base + i]);
  float x2 = bf2f(buf[base + i + 32]);
  buf[base + i]      = f2bf(x1 * c - x2 * sn);
  buf[base + i + 32] = f2bf(x2 * c + x1 * sn);
}

// ---------------------------------------------------------------------------
// V pre-transpose with PV k-slot permutation baked in (one-shot, ~8MB traffic).
// In:  Vsrc[b*2048 + s][kvoff + d]  (row stride vs)
// Out: Vtp[((b*8+kv)*64 + d)*2048 + t*64 + cperm(k_local)] = Vsrc value
// cperm: c5=k5, c4c3=k3k2, c2=k4, c1c0=k1k0; inverse applied at write.
// ---------------------------------------------------------------------------
__global__ void vtrans(const short* __restrict__ Vsrc, int vs, short* __restrict__ Vtp) {
  const int t = blockIdx.x, kv = blockIdx.y, b = blockIdx.z;
  __shared__ short lt[64][72];
  const int kl = threadIdx.x >> 2;
  const int dq = (threadIdx.x & 3) * 16;
  const short* src = Vsrc + (size_t)(b * S_LEN + t * 64 + kl) * vs + kv * 64 + dq;
  bf16x8 v0 = *(const bf16x8*)src;
  bf16x8 v1 = *(const bf16x8*)(src + 8);
  *(bf16x8*)&lt[kl][dq]     = v0;
  *(bf16x8*)&lt[kl][dq + 8] = v1;
  __syncthreads();
  const int d  = threadIdx.x >> 2;
  const int cb = (threadIdx.x & 3) * 16;
  bf16x8 o0, o1;
#pragma unroll
  for (int j = 0; j < 8; ++j) {
    const int c  = cb + j;
    const int k  = (c & 32) | (((c >> 2) & 1) << 4) | (((c >> 3) & 3) << 2) | (c & 3);
    o0[j] = lt[k][d];
    const int c2 = cb + 8 + j;
    const int k2 = (c2 & 32) | (((c2 >> 2) & 1) << 4) | (((c2 >> 3) & 3) << 2) | (c2 & 3);
    o1[j] = lt[k2][d];
  }
  short* dst = Vtp + (size_t)((b * N_KV + kv) * 64 + d) * S_LEN + t * 64 + cb;
  *(bf16x8*)dst       = o0;
  *(bf16x8*)(dst + 8) = o1;
}

// ---------------------------------------------------------------------------
// Flash attention helpers (double-swapped MFMA layout).
// ---------------------------------------------------------------------------
__device__ __forceinline__ void qkt_mfma(const bf16x8 (&kf)[4][2],
                                         const bf16x8 (&qa)[2][2],
                                         f32x4 (&sf)[2][4]) {
  __builtin_amdgcn_s_setprio(1);
#pragma unroll
  for (int nf = 0; nf < 4; ++nf)
#pragma unroll
    for (int fr = 0; fr < 2; ++fr) {
      f32x4 t = {};
      t = __builtin_amdgcn_mfma_f32_16x16x32_bf16(kf[nf][0], qa[fr][0], t, 0, 0, 0);
      t = __builtin_amdgcn_mfma_f32_16x16x32_bf16(kf[nf][1], qa[fr][1], t, 0, 0, 0);
      sf[fr][nf] = t;
    }
  __builtin_amdgcn_s_setprio(0);
}

template <int KS>
__device__ __forceinline__ void load_kf(bf16x8 (&kf)[4][2], const short* kbase, int t) {
  const short* kp = kbase + (size_t)t * 64 * KS;
#pragma unroll
  for (int nf = 0; nf < 4; ++nf) {
    kf[nf][0] = *(const bf16x8*)(kp + (size_t)nf * 16 * KS);
    kf[nf][1] = *(const bf16x8*)(kp + (size_t)nf * 16 * KS + 32);
  }
}

// PV B-operand fragments straight from pre-transposed global V (b128, L2-hot).
__device__ __forceinline__ void load_vbg(bf16x8 (&vb)[2][4], const short* vtbase,
                                         int t, int lr, int lg) {
#pragma unroll
  for (int ks2 = 0; ks2 < 2; ++ks2)
#pragma unroll
    for (int df = 0; df < 4; ++df)
      vb[ks2][df] = *(const bf16x8*)(vtbase + (size_t)(df * 16 + lr) * S_LEN
                                     + t * 64 + ks2 * 32 + lg * 8);
}

__device__ __forceinline__ void softmax_pv(
    f32x4 (&sf)[2][4], const bf16x8 (&vb)[2][4], f32x4 (&o)[2][4],
    float (&mrow)[2], float (&msc)[2], float (&lsum)[2],
    float SC, float THRR) {
  bf16x8 pa[2][2];
#pragma unroll
  for (int fr = 0; fr < 2; ++fr) {
    float lmax = fmaxf(fmaxf(sf[fr][0][0], sf[fr][0][1]), fmaxf(sf[fr][0][2], sf[fr][0][3]));
#pragma unroll
    for (int nf = 1; nf < 4; ++nf) {
      float m01 = fmaxf(sf[fr][nf][0], sf[fr][nf][1]);
      float m23 = fmaxf(sf[fr][nf][2], sf[fr][nf][3]);
      lmax = fmaxf(lmax, fmaxf(m01, m23));
    }
    // speculative defer-max: rare path only when lane-local max grew past thr
    if (!__all(lmax <= mrow[fr] + THRR)) {
      float mx = fmaxf(lmax, __shfl_xor(lmax, 16));
      mx = fmaxf(mx, __shfl_xor(mx, 32));
      const float mnew  = fmaxf(mrow[fr], mx);
      const float alpha = exp2f((mrow[fr] - mnew) * SC);
      mrow[fr] = mnew;
      msc[fr]  = mnew * SC;
      lsum[fr] *= alpha;
#pragma unroll
      for (int df = 0; df < 4; ++df) o[fr][df] *= alpha;
    }
    const float nm = msc[fr];
#pragma unroll
    for (int nf = 0; nf < 4; ++nf)
#pragma unroll
      for (int r = 0; r < 4; ++r)
        sf[fr][nf][r] = exp2f(fmaf(sf[fr][nf][r], SC, -nm));
    // tree-reduced denominator (fp32 adds are not compiler-reassociated)
    {
      float t0 = (sf[fr][0][0] + sf[fr][0][1]) + (sf[fr][0][2] + sf[fr][0][3]);
      float t1 = (sf[fr][1][0] + sf[fr][1][1]) + (sf[fr][1][2] + sf[fr][1][3]);
      float t2 = (sf[fr][2][0] + sf[fr][2][1]) + (sf[fr][2][2] + sf[fr][2][3]);
      float t3 = (sf[fr][3][0] + sf[fr][3][1]) + (sf[fr][3][2] + sf[fr][3][3]);
      lsum[fr] += (t0 + t1) + (t2 + t3);
    }
#pragma unroll
    for (int ks2 = 0; ks2 < 2; ++ks2) {
      u32x4 pk;
      pk[0] = cvtpk(sf[fr][2 * ks2][0], sf[fr][2 * ks2][1]);
      pk[1] = cvtpk(sf[fr][2 * ks2][2], sf[fr][2 * ks2][3]);
      pk[2] = cvtpk(sf[fr][2 * ks2 + 1][0], sf[fr][2 * ks2 + 1][1]);
      pk[3] = cvtpk(sf[fr][2 * ks2 + 1][2], sf[fr][2 * ks2 + 1][3]);
      pa[fr][ks2] = __builtin_bit_cast(bf16x8, pk);
    }
  }
  __builtin_amdgcn_s_setprio(1);
#pragma unroll
  for (int ks2 = 0; ks2 < 2; ++ks2)
#pragma unroll
    for (int fr = 0; fr < 2; ++fr)
#pragma unroll
      for (int df = 0; df < 4; ++df)
        o[fr][df] = __builtin_amdgcn_mfma_f32_16x16x32_bf16(vb[ks2][df], pa[fr][ks2], o[fr][df], 0, 0, 0);
  __builtin_amdgcn_s_setprio(0);
}

// ---------------------------------------------------------------------------
// Flash attention: NO LDS, NO BARRIERS. K fragments and pre-transposed V
// fragments both read directly from global (L2-resident); waves fully
// independent. 2-tile QK^T software pipeline kept for MFMA/VALU overlap.
// Grid (S/128, NH, B), 256 thr = 4 independent waves, wave owns 32 q-rows.
// ---------------------------------------------------------------------------
#define NT (S_LEN / 64)
template <int QS, int KS, int OS>
__launch_bounds__(256, 2)
__global__ void attn_kernel(const short* __restrict__ Q, const short* __restrict__ K,
                            const short* __restrict__ Vtp, short* __restrict__ O) {
  const int qt = blockIdx.x, h = blockIdx.y, b = blockIdx.z;
  const int kv = h >> 2;
  const int tid  = threadIdx.x;
  const int lane = tid & 63, w = tid >> 6;
  const int lr = lane & 15, lg = lane >> 4;

  const int q0 = qt * 128 + w * 32;
  bf16x8 qa[2][2];
#pragma unroll
  for (int fr = 0; fr < 2; ++fr) {
    const short* qp = Q + (size_t)(b * S_LEN + q0 + fr * 16 + lr) * QS + h * HEAD_DIM + lg * 8;
    qa[fr][0] = *(const bf16x8*)qp;
    qa[fr][1] = *(const bf16x8*)(qp + 32);
  }

  f32x4 o[2][4] = {};
  float mrow[2] = {-1e30f, -1e30f};
  float msc[2]  = {-1e30f, -1e30f};
  float lsum[2] = {0.f, 0.f};

  const short* vtbase = Vtp + (size_t)((b * N_KV + kv) * 64) * S_LEN;
  const short* kbase  = K + (size_t)(b * S_LEN + lr) * KS + kv * HEAD_DIM + lg * 8;

  const float SC   = 0.125f * 1.4426950408889634f;   // HD^-0.5 * log2(e)
  const float THRR = 8.0f / SC;

  // ---- prologue ----
  bf16x8 kf[4][2];
  bf16x8 vb[2][4];
  f32x4 sfA[2][4], sfB[2][4];
  load_kf<KS>(kf, kbase, 0);
  qkt_mfma(kf, qa, sfA);
  load_kf<KS>(kf, kbase, 1);

  for (int t = 0; t < NT; t += 2) {
    // ===== phase A: tile t =====
    load_vbg(vb, vtbase, t, lr, lg);           // L2 latency hidden by QK^T+SM
    qkt_mfma(kf, qa, sfB);                     // QK^T(t+1), kf = K(t+1)
    if (t + 2 < NT) load_kf<KS>(kf, kbase, t + 2);
    softmax_pv(sfA, vb, o, mrow, msc, lsum, SC, THRR);

    // ===== phase B: tile t+1 =====
    load_vbg(vb, vtbase, t + 1, lr, lg);
    if (t + 2 < NT) {
      qkt_mfma(kf, qa, sfA);                   // QK^T(t+2), kf = K(t+2)
      if (t + 3 < NT) load_kf<KS>(kf, kbase, t + 3);
    }
    softmax_pv(sfB, vb, o, mrow, msc, lsum, SC, THRR);
  }

  // ---- epilogue: combine lane-partial denominators once, then store ----
#pragma unroll
  for (int fr = 0; fr < 2; ++fr) {
    float ls = lsum[fr];
    ls += __shfl_xor(ls, 16);
    ls += __shfl_xor(ls, 32);
    const float invl = 1.0f / ls;
    const size_t orow = (size_t)(b * S_LEN + q0 + fr * 16 + lr) * OS + h * HEAD_DIM;
#pragma unroll
    for (int df = 0; df < 4; ++df) {
      u32x2 pk;
      pk[0] = cvtpk(o[fr][df][0] * invl, o[fr][df][1] * invl);
      pk[1] = cvtpk(o[fr][df][2] * invl, o[fr][df][3] * invl);
      *(u32x2*)&O[orow + df * 16 + 4 * lg] = pk;
    }
  }
}

// ---------------------------------------------------------------------------
extern "C" void kernel_launch(void* const* d_in, const int* in_sizes, int n_in,
                              void* d_out, int out_size, void* d_ws, size_t ws_size,
                              hipStream_t stream) {
  (void)in_sizes; (void)n_in; (void)out_size;
  const float* hidden = (const float*)d_in[0];
  const float* wq = (const float*)d_in[1];
  const float* wk = (const float*)d_in[2];
  const float* wv = (const float*)d_in[3];
  const float* wo = (const float*)d_in[4];
  float* out = (float*)d_out;

  const int M = 2 * S_LEN;                        // 4096
  const size_t nHid  = (size_t)M * HIDDEN;        // 8388608
  const size_t nW    = (size_t)HIDDEN * HIDDEN;   // 4194304
  const size_t nWkv  = (size_t)KVD * HIDDEN;      // 1048576
  const size_t nWcat = nW + 2 * nWkv;             // 6291456  (wq|wk|wv rows)
  const int    NQKV  = HIDDEN + 2 * KVD;          // 3072
  const size_t nQKV  = (size_t)M * NQKV;          // 12582912
  const size_t nVtp  = (size_t)M * KVD;           // 2097152

  const size_t fastElems = nHid + nWcat + nW + nQKV + nHid;  // 39845888
  if (ws_size >= fastElems * sizeof(short)) {
    short* hb   = (short*)d_ws;
    short* wcat = hb + nHid;          // [3072][2048]: wq rows, wk rows, wv rows
    short* wob  = wcat + nWcat;
    short* QKV  = wob + nW;           // [4096][3072]: Q | K | V
    short* AO   = QKV + nQKV;
    short* vtp  = hb;                 // reuse hb (dead after QKV GEMM); 2.1M <= 8.4M

    CvtArgs ca;
    ca.src[0] = hidden; ca.dst[0] = hb;            ca.cnt4[0] = (int)(nHid / 4);
    ca.src[1] = wq;     ca.dst[1] = wcat;          ca.cnt4[1] = (int)(nW / 4);
    ca.src[2] = wk;     ca.dst[2] = wcat + nW;     ca.cnt4[2] = (int)(nWkv / 4);
    ca.src[3] = wv;     ca.dst[3] = wcat + nW + nWkv; ca.cnt4[3] = (int)(nWkv / 4);
    ca.src[4] = wo;     ca.dst[4] = wob;           ca.cnt4[4] = (int)(nW / 4);
    const int total4 = (int)((nHid + nWcat + nW) / 4);
    cvt_bf16<<<2048, 256, 0, stream>>>(ca, total4);

    // fused QKV projection: [4096,3072] = hb @ wcat^T
    gemm_lds<short><<<dim3(NQKV / 128, 32), 256, 0, stream>>>(hb, wcat, QKV, M, NQKV, HIDDEN);
    // V pre-transpose+perm (hb is dead now; vtp aliases it)
    vtrans<<<dim3(S_LEN / 64, N_KV, 2), 256, 0, stream>>>(QKV + HIDDEN + KVD, NQKV, vtp);
    // fused RoPE over Q(32 heads) + K(8 heads) = cols 0..2559
    const int rtot = M * 40 * 32;
    rope_kernel<40><<<(rtot + 255) / 256, 256, 0, stream>>>(QKV, NQKV, rtot);
    // attention: Q at col 0, K at col 2048 of QKV; V from vtp
    attn_kernel<3072, 3072, HIDDEN><<<dim3(S_LEN / 128, N_HEADS, 2), 256, 0, stream>>>(
        QKV, QKV + HIDDEN, vtp, AO);
    // output projection
    gemm_lds<float><<<dim3(16, 32), 256, 0, stream>>>(AO, wob, out, M, HIDDEN, HIDDEN);
  } else {
    short* Qb  = (short*)d_ws;
    short* Kb  = Qb + nHid;
    short* Vb  = Kb + nVtp;
    short* AO  = Vb + nVtp;
    short* vtp = AO + nHid;
    gemm_bt<float, short><<<dim3(16, 32), 256, 0, stream>>>(hidden, wq, Qb, M, HIDDEN, HIDDEN);
    gemm_bt<float, short><<<dim3(4, 32), 256, 0, stream>>>(hidden, wk, Kb, M, KVD, HIDDEN);
    gemm_bt<float, short><<<dim3(4, 32), 256, 0, stream>>>(hidden, wv, Vb, M, KVD, HIDDEN);
    const int rq = M * N_HEADS * 32, rk = M * N_KV * 32;
    rope_kernel<N_HEADS><<<(rq + 255) / 256, 256, 0, stream>>>(Qb, HIDDEN, rq);
    rope_kernel<N_KV><<<(rk + 255) / 256, 256, 0, stream>>>(Kb, KVD, rk);
    vtrans<<<dim3(S_LEN / 64, N_KV, 2), 256, 0, stream>>>(Vb, KVD, vtp);
    attn_kernel<HIDDEN, KVD, HIDDEN><<<dim3(S_LEN / 128, N_HEADS, 2), 256, 0, stream>>>(
        Qb, Kb, vtp, AO);
    gemm_bt<short, float><<<dim3(16, 32), 256, 0, stream>>>(AO, wo, out, M, HIDDEN, HIDDEN);
  }
}

// Round 10
// 283.933 us; speedup vs baseline: 1.3005x; 1.3005x over previous
//
#include <hip/hip_runtime.h>
#include <stdint.h>

typedef __attribute__((ext_vector_type(8))) short bf16x8;
typedef __attribute__((ext_vector_type(4))) short bf16x4;
typedef __attribute__((ext_vector_type(4))) float f32x4;
typedef __attribute__((ext_vector_type(4))) unsigned u32x4;
typedef __attribute__((ext_vector_type(2))) unsigned u32x2;

#define S_LEN 2048
#define HIDDEN 2048
#define N_HEADS 32
#define N_KV 8
#define HEAD_DIM 64
#define KVD (N_KV * HEAD_DIM)   // 512

__device__ __forceinline__ float bf2f(short u) {
  return __builtin_bit_cast(float, ((unsigned)(unsigned short)u) << 16);
}
__device__ __forceinline__ short f2bf(float f) {
  unsigned u = __builtin_bit_cast(unsigned, f);
  u += 0x7FFFu + ((u >> 16) & 1u);
  return (short)(u >> 16);
}
__device__ __forceinline__ unsigned cvtpk(float lo, float hi) {
  unsigned r;
  asm("v_cvt_pk_bf16_f32 %0, %1, %2" : "=v"(r) : "v"(lo), "v"(hi));
  return r;
}
__device__ __forceinline__ bf16x8 cvt8(f32x4 lo, f32x4 hi) {
  bf16x8 r;
#pragma unroll
  for (int j = 0; j < 4; ++j) { r[j] = f2bf(lo[j]); r[j + 4] = f2bf(hi[j]); }
  return r;
}
__device__ __forceinline__ void storeC(float* p, float v) { *p = v; }
__device__ __forceinline__ void storeC(short* p, float v) { *p = f2bf(v); }

__device__ __forceinline__ void gll16(const void* g, void* l) {
  __builtin_amdgcn_global_load_lds(
      (const __attribute__((address_space(1))) void*)g,
      (__attribute__((address_space(3))) void*)l, 16, 0, 0);
}

// ---------------------------------------------------------------------------
// fp32 -> bf16 bulk convert, 5 segments, grid-stride, float4 units.
// ---------------------------------------------------------------------------
struct CvtArgs {
  const float* src[5];
  short* dst[5];
  int cnt4[5];
};
__global__ void cvt_bf16(CvtArgs a, int total4) {
  int u = blockIdx.x * 256 + threadIdx.x;
  const int stride = gridDim.x * 256;
  for (; u < total4; u += stride) {
    int s = 0, off = u;
    while (off >= a.cnt4[s]) { off -= a.cnt4[s]; ++s; }
    f32x4 v = *(const f32x4*)(a.src[s] + (size_t)off * 4);
    bf16x4 r;
#pragma unroll
    for (int j = 0; j < 4; ++j) r[j] = f2bf(v[j]);
    *(bf16x4*)(a.dst[s] + (size_t)off * 4) = r;
  }
}

// ---------------------------------------------------------------------------
// FAST GEMM (m97 structure): C[M,N] = A[M,K] @ W[N,K]^T, bf16 in, bf16/fp32 out.
// ---------------------------------------------------------------------------
template <typename CT>
__launch_bounds__(256, 3)
__global__ void gemm_lds(const short* __restrict__ A, const short* __restrict__ W,
                         CT* __restrict__ C, int M, int N, int K) {
  __shared__ short As[128 * 32];
  __shared__ short Ws[128 * 32];
  const int tid  = threadIdx.x;
  const int lane = tid & 63;
  const int w    = tid >> 6;
  const int wm = w >> 1, wn = w & 1;
  const int lr = lane & 15, lg = lane >> 4;
  const int m0 = blockIdx.y * 128, n0 = blockIdx.x * 128;

  const size_t a0 = (size_t)(m0 + w * 16 + (lane >> 2)) * K + (lane & 3) * 8;
  const size_t a1 = a0 + (size_t)64 * K;
  const size_t b0 = (size_t)(n0 + w * 16 + (lane >> 2)) * K + (lane & 3) * 8;
  const size_t b1 = b0 + (size_t)64 * K;
  short* lA0 = &As[(w * 16) * 32];
  short* lA1 = &As[(64 + w * 16) * 32];
  short* lB0 = &Ws[(w * 16) * 32];
  short* lB1 = &Ws[(64 + w * 16) * 32];

  f32x4 acc[4][4] = {};

  for (int k0 = 0; k0 < K; k0 += 32) {
    __syncthreads();
    gll16(A + a0 + k0, lA0);
    gll16(A + a1 + k0, lA1);
    gll16(W + b0 + k0, lB0);
    gll16(W + b1 + k0, lB1);
    __syncthreads();
    bf16x8 af[4], bfr[4];
#pragma unroll
    for (int i = 0; i < 4; ++i) {
      af[i]  = *(const bf16x8*)&As[(wm * 64 + i * 16 + lr) * 32 + lg * 8];
      bfr[i] = *(const bf16x8*)&Ws[(wn * 64 + i * 16 + lr) * 32 + lg * 8];
    }
#pragma unroll
    for (int i = 0; i < 4; ++i)
#pragma unroll
      for (int j = 0; j < 4; ++j)
        acc[i][j] = __builtin_amdgcn_mfma_f32_16x16x32_bf16(af[i], bfr[j], acc[i][j], 0, 0, 0);
  }

#pragma unroll
  for (int i = 0; i < 4; ++i)
#pragma unroll
    for (int j = 0; j < 4; ++j) {
      const int row = m0 + wm * 64 + i * 16 + lg * 4;
      const int col = n0 + wn * 64 + j * 16 + lr;
#pragma unroll
      for (int r = 0; r < 4; ++r)
        storeC(&C[(size_t)(row + r) * N + col], acc[i][j][r]);
    }
}

// ---------------------------------------------------------------------------
// FALLBACK GEMM (register-staged, converts fp32 in flight).
// ---------------------------------------------------------------------------
template <typename AT, typename CT>
__launch_bounds__(256, 2)
__global__ void gemm_bt(const AT* __restrict__ A, const float* __restrict__ W,
                        CT* __restrict__ C, int M, int N, int K) {
  __shared__ short As[128][40];
  __shared__ short Ws[128][40];
  const int tid  = threadIdx.x;
  const int lane = tid & 63;
  const int wid  = tid >> 6;
  const int wm = wid >> 1, wn = wid & 1;
  const int lr = lane & 15, lg = lane >> 4;
  const int m0 = blockIdx.y * 128, n0 = blockIdx.x * 128;
  const int srow = tid >> 2;
  const int scol = (tid & 3) * 8;

  f32x4 acc[4][4] = {};
  const AT*    Ap = A + (size_t)(m0 + srow) * K + scol;
  const float* Wp = W + (size_t)(n0 + srow) * K + scol;

  for (int k0 = 0; k0 < K; k0 += 32) {
    bf16x8 a0, a1, b0, b1;
    if constexpr (sizeof(AT) == 4) {
      a0 = cvt8(*(const f32x4*)(Ap + k0), *(const f32x4*)(Ap + k0 + 4));
      a1 = cvt8(*(const f32x4*)(Ap + (size_t)64 * K + k0),
                *(const f32x4*)(Ap + (size_t)64 * K + k0 + 4));
    } else {
      a0 = *(const bf16x8*)(Ap + k0);
      a1 = *(const bf16x8*)(Ap + (size_t)64 * K + k0);
    }
    b0 = cvt8(*(const f32x4*)(Wp + k0), *(const f32x4*)(Wp + k0 + 4));
    b1 = cvt8(*(const f32x4*)(Wp + (size_t)64 * K + k0),
              *(const f32x4*)(Wp + (size_t)64 * K + k0 + 4));
    __syncthreads();
    *(bf16x8*)&As[srow][scol]      = a0;
    *(bf16x8*)&As[srow + 64][scol] = a1;
    *(bf16x8*)&Ws[srow][scol]      = b0;
    *(bf16x8*)&Ws[srow + 64][scol] = b1;
    __syncthreads();
    bf16x8 af[4], bfr[4];
#pragma unroll
    for (int i = 0; i < 4; ++i) {
      af[i]  = *(const bf16x8*)&As[wm * 64 + i * 16 + lr][lg * 8];
      bfr[i] = *(const bf16x8*)&Ws[wn * 64 + i * 16 + lr][lg * 8];
    }
#pragma unroll
    for (int i = 0; i < 4; ++i)
#pragma unroll
      for (int j = 0; j < 4; ++j)
        acc[i][j] = __builtin_amdgcn_mfma_f32_16x16x32_bf16(af[i], bfr[j], acc[i][j], 0, 0, 0);
  }
#pragma unroll
  for (int i = 0; i < 4; ++i)
#pragma unroll
    for (int j = 0; j < 4; ++j) {
      const int row = m0 + wm * 64 + i * 16 + lg * 4;
      const int col = n0 + wn * 64 + j * 16 + lr;
#pragma unroll
      for (int r = 0; r < 4; ++r)
        storeC(&C[(size_t)(row + r) * N + col], acc[i][j][r]);
    }
}

// ---------------------------------------------------------------------------
// RoPE, head h -> cols 64h..64h+63 of a [rows, rowstride] bf16 buffer.
// ---------------------------------------------------------------------------
template <int NH>
__global__ void rope_kernel(short* __restrict__ buf, int rowstride, int total) {
  int idx = blockIdx.x * 256 + threadIdx.x;
  if (idx >= total) return;
  const int i   = idx & 31;
  const int hh  = (idx >> 5) % NH;
  const int row = (idx >> 5) / NH;
  const int pos = row & (S_LEN - 1);
  const float invf = exp2f(-(float)i * (13.287712379549449f / 32.0f));
  const float ang  = (float)pos * invf;
  float sn, c;
  sincosf(ang, &sn, &c);
  size_t base = (size_t)row * rowstride + hh * 64;
  float x1 = bf2f(buf[base + i]);
  float x2 = bf2f(buf[base + i + 32]);
  buf[base + i]      = f2bf(x1 * c - x2 * sn);
  buf[base + i + 32] = f2bf(x2 * c + x1 * sn);
}

// ---------------------------------------------------------------------------
// V pre-transpose; PV k-slot permutation AND read-side XOR swizzle baked in.
// Out: Vtp[((b*8+kv)*64 + d)*2048 + t*64 + c_phys] = V[t*64 + k][d]
//   where cperm(k) = c_phys ^ ((d&7)<<3),
//   cperm: c5=k5, c4c3=k3k2, c2=k4, c1c0=k1k0.
// attn stages this linearly via global_load_lds and un-XORs on ds_read.
// ---------------------------------------------------------------------------
__global__ void vtrans(const short* __restrict__ Vsrc, int vs, short* __restrict__ Vtp) {
  const int t = blockIdx.x, kv = blockIdx.y, b = blockIdx.z;
  __shared__ short lt[64][72];
  const int kl = threadIdx.x >> 2;
  const int dq = (threadIdx.x & 3) * 16;
  const short* src = Vsrc + (size_t)(b * S_LEN + t * 64 + kl) * vs + kv * 64 + dq;
  bf16x8 v0 = *(const bf16x8*)src;
  bf16x8 v1 = *(const bf16x8*)(src + 8);
  *(bf16x8*)&lt[kl][dq]     = v0;
  *(bf16x8*)&lt[kl][dq + 8] = v1;
  __syncthreads();
  const int d  = threadIdx.x >> 2;
  const int cb = (threadIdx.x & 3) * 16;
  const int xm = (d & 7) << 3;
  const int c0 = cb ^ xm;          // logical col base for physical cb..cb+7
  const int c1 = c0 ^ 8;           // for physical cb+8..cb+15
  bf16x8 o0, o1;
#pragma unroll
  for (int j = 0; j < 8; ++j) {
    const int ca = c0 + j;
    const int ka = (ca & 32) | (((ca >> 2) & 1) << 4) | (((ca >> 3) & 3) << 2) | (ca & 3);
    o0[j] = lt[ka][d];
    const int cbb = c1 + j;
    const int kb = (cbb & 32) | (((cbb >> 2) & 1) << 4) | (((cbb >> 3) & 3) << 2) | (cbb & 3);
    o1[j] = lt[kb][d];
  }
  short* dst = Vtp + (size_t)((b * N_KV + kv) * 64 + d) * S_LEN + t * 64 + cb;
  *(bf16x8*)dst       = o0;
  *(bf16x8*)(dst + 8) = o1;
}

// ---------------------------------------------------------------------------
// Flash attention helpers (double-swapped MFMA layout).
// ---------------------------------------------------------------------------
__device__ __forceinline__ void qkt_mfma(const bf16x8 (&kf)[4][2],
                                         const bf16x8 (&qa)[2][2],
                                         f32x4 (&sf)[2][4]) {
  __builtin_amdgcn_s_setprio(1);
#pragma unroll
  for (int nf = 0; nf < 4; ++nf)
#pragma unroll
    for (int fr = 0; fr < 2; ++fr) {
      f32x4 t = {};
      t = __builtin_amdgcn_mfma_f32_16x16x32_bf16(kf[nf][0], qa[fr][0], t, 0, 0, 0);
      t = __builtin_amdgcn_mfma_f32_16x16x32_bf16(kf[nf][1], qa[fr][1], t, 0, 0, 0);
      sf[fr][nf] = t;
    }
  __builtin_amdgcn_s_setprio(0);
}

template <int KS>
__device__ __forceinline__ void load_kf(bf16x8 (&kf)[4][2], const short* kbase, int t) {
  const short* kp = kbase + (size_t)t * 64 * KS;
#pragma unroll
  for (int nf = 0; nf < 4; ++nf) {
    kf[nf][0] = *(const bf16x8*)(kp + (size_t)nf * 16 * KS);
    kf[nf][1] = *(const bf16x8*)(kp + (size_t)nf * 16 * KS + 32);
  }
}

// Stage one 64x64 V tile (pre-swizzled layout) into linear LDS: 2 gll16/wave.
__device__ __forceinline__ void stage_v(short* lds, const short* vtbase, int t,
                                        int w, int lane) {
  const int l3 = lane >> 3, l7 = lane & 7;
#pragma unroll
  for (int ci = 0; ci < 2; ++ci) {
    const int call = 2 * w + ci;
    const int d = call * 8 + l3;
    gll16(vtbase + (size_t)d * S_LEN + t * 64 + l7 * 8, lds + call * 512);
  }
}

// PV B-operand reads from LDS with the XOR un-swizzle (conflict-free b128).
__device__ __forceinline__ void load_vb(bf16x8 (&vb)[2][4], const short* lds,
                                        int lr, int lg) {
  const int xm = (lr & 7) << 3;
#pragma unroll
  for (int ks2 = 0; ks2 < 2; ++ks2)
#pragma unroll
    for (int df = 0; df < 4; ++df)
      vb[ks2][df] = *(const bf16x8*)&lds[(df * 16 + lr) * 64 + ((ks2 * 32 + lg * 8) ^ xm)];
}

__device__ __forceinline__ void softmax_pv(
    f32x4 (&sf)[2][4], const bf16x8 (&vb)[2][4], f32x4 (&o)[2][4],
    float (&mrow)[2], float (&msc)[2], float (&lsum)[2],
    float SC, float THRR) {
  bf16x8 pa[2][2];
#pragma unroll
  for (int fr = 0; fr < 2; ++fr) {
    float lmax = fmaxf(fmaxf(sf[fr][0][0], sf[fr][0][1]), fmaxf(sf[fr][0][2], sf[fr][0][3]));
#pragma unroll
    for (int nf = 1; nf < 4; ++nf) {
      float m01 = fmaxf(sf[fr][nf][0], sf[fr][nf][1]);
      float m23 = fmaxf(sf[fr][nf][2], sf[fr][nf][3]);
      lmax = fmaxf(lmax, fmaxf(m01, m23));
    }
    // speculative defer-max: rare path only when lane-local max grew past thr
    if (!__all(lmax <= mrow[fr] + THRR)) {
      float mx = fmaxf(lmax, __shfl_xor(lmax, 16));
      mx = fmaxf(mx, __shfl_xor(mx, 32));
      const float mnew  = fmaxf(mrow[fr], mx);
      const float alpha = __builtin_amdgcn_exp2f((mrow[fr] - mnew) * SC);
      mrow[fr] = mnew;
      msc[fr]  = mnew * SC;
      lsum[fr] *= alpha;
#pragma unroll
      for (int df = 0; df < 4; ++df) o[fr][df] *= alpha;
    }
    const float nm = msc[fr];
#pragma unroll
    for (int nf = 0; nf < 4; ++nf)
#pragma unroll
      for (int r = 0; r < 4; ++r)
        sf[fr][nf][r] = __builtin_amdgcn_exp2f(fmaf(sf[fr][nf][r], SC, -nm));
    // tree-reduced denominator
    {
      float t0 = (sf[fr][0][0] + sf[fr][0][1]) + (sf[fr][0][2] + sf[fr][0][3]);
      float t1 = (sf[fr][1][0] + sf[fr][1][1]) + (sf[fr][1][2] + sf[fr][1][3]);
      float t2 = (sf[fr][2][0] + sf[fr][2][1]) + (sf[fr][2][2] + sf[fr][2][3]);
      float t3 = (sf[fr][3][0] + sf[fr][3][1]) + (sf[fr][3][2] + sf[fr][3][3]);
      lsum[fr] += (t0 + t1) + (t2 + t3);
    }
#pragma unroll
    for (int ks2 = 0; ks2 < 2; ++ks2) {
      u32x4 pk;
      pk[0] = cvtpk(sf[fr][2 * ks2][0], sf[fr][2 * ks2][1]);
      pk[1] = cvtpk(sf[fr][2 * ks2][2], sf[fr][2 * ks2][3]);
      pk[2] = cvtpk(sf[fr][2 * ks2 + 1][0], sf[fr][2 * ks2 + 1][1]);
      pk[3] = cvtpk(sf[fr][2 * ks2 + 1][2], sf[fr][2 * ks2 + 1][3]);
      pa[fr][ks2] = __builtin_bit_cast(bf16x8, pk);
    }
  }
  __builtin_amdgcn_s_setprio(1);
#pragma unroll
  for (int ks2 = 0; ks2 < 2; ++ks2)
#pragma unroll
    for (int fr = 0; fr < 2; ++fr)
#pragma unroll
      for (int df = 0; df < 4; ++df)
        o[fr][df] = __builtin_amdgcn_mfma_f32_16x16x32_bf16(vb[ks2][df], pa[fr][ks2], o[fr][df], 0, 0, 0);
  __builtin_amdgcn_s_setprio(0);
}

// ---------------------------------------------------------------------------
// Flash attention: V staged to LDS via global_load_lds from the pre-swizzled
// Vtp (stage issued one full tile early, latency hidden); K frags from global;
// 2-tile QK^T software pipeline; 1 barrier per tile.
// Grid (S/128, NH, B), 256 thr = 4 waves, wave owns 32 q-rows.
// ---------------------------------------------------------------------------
#define NT (S_LEN / 64)
template <int QS, int KS, int OS>
__launch_bounds__(256, 2)
__global__ void attn_kernel(const short* __restrict__ Q, const short* __restrict__ K,
                            const short* __restrict__ Vtp, short* __restrict__ O) {
  const int qt = blockIdx.x, h = blockIdx.y, b = blockIdx.z;
  const int kv = h >> 2;
  const int tid  = threadIdx.x;
  const int lane = tid & 63, w = tid >> 6;
  const int lr = lane & 15, lg = lane >> 4;

  __shared__ short Vt[2][64 * 64];   // [buf][d][c_phys] linear, 8KB each

  const int q0 = qt * 128 + w * 32;
  bf16x8 qa[2][2];
#pragma unroll
  for (int fr = 0; fr < 2; ++fr) {
    const short* qp = Q + (size_t)(b * S_LEN + q0 + fr * 16 + lr) * QS + h * HEAD_DIM + lg * 8;
    qa[fr][0] = *(const bf16x8*)qp;
    qa[fr][1] = *(const bf16x8*)(qp + 32);
  }

  f32x4 o[2][4] = {};
  float mrow[2] = {-1e30f, -1e30f};
  float msc[2]  = {-1e30f, -1e30f};
  float lsum[2] = {0.f, 0.f};

  const short* vtbase = Vtp + (size_t)((b * N_KV + kv) * 64) * S_LEN;
  const short* kbase  = K + (size_t)(b * S_LEN + lr) * KS + kv * HEAD_DIM + lg * 8;

  const float SC   = 0.125f * 1.4426950408889634f;   // HD^-0.5 * log2(e)
  const float THRR = 8.0f / SC;

  // ---- prologue ----
  bf16x8 kf[4][2];
  bf16x8 vb[2][4];
  f32x4 sfA[2][4], sfB[2][4];
  stage_v(Vt[0], vtbase, 0, w, lane);
  load_kf<KS>(kf, kbase, 0);
  qkt_mfma(kf, qa, sfA);
  load_kf<KS>(kf, kbase, 1);
  __syncthreads();                                  // V(0) staged

  for (int t = 0; t < NT; t += 2) {
    // ===== phase A: tile t (buf0) =====
    load_vb(vb, Vt[0], lr, lg);
    stage_v(Vt[1], vtbase, t + 1, w, lane);         // async, lands by barrier
    qkt_mfma(kf, qa, sfB);                          // QK^T(t+1)
    if (t + 2 < NT) load_kf<KS>(kf, kbase, t + 2);
    softmax_pv(sfA, vb, o, mrow, msc, lsum, SC, THRR);
    __syncthreads();

    // ===== phase B: tile t+1 (buf1) =====
    load_vb(vb, Vt[1], lr, lg);
    if (t + 2 < NT) {
      stage_v(Vt[0], vtbase, t + 2, w, lane);
      qkt_mfma(kf, qa, sfA);                        // QK^T(t+2)
      if (t + 3 < NT) load_kf<KS>(kf, kbase, t + 3);
    }
    softmax_pv(sfB, vb, o, mrow, msc, lsum, SC, THRR);
    __syncthreads();
  }

  // ---- epilogue ----
#pragma unroll
  for (int fr = 0; fr < 2; ++fr) {
    float ls = lsum[fr];
    ls += __shfl_xor(ls, 16);
    ls += __shfl_xor(ls, 32);
    const float invl = 1.0f / ls;
    const size_t orow = (size_t)(b * S_LEN + q0 + fr * 16 + lr) * OS + h * HEAD_DIM;
#pragma unroll
    for (int df = 0; df < 4; ++df) {
      u32x2 pk;
      pk[0] = cvtpk(o[fr][df][0] * invl, o[fr][df][1] * invl);
      pk[1] = cvtpk(o[fr][df][2] * invl, o[fr][df][3] * invl);
      *(u32x2*)&O[orow + df * 16 + 4 * lg] = pk;
    }
  }
}

// ---------------------------------------------------------------------------
extern "C" void kernel_launch(void* const* d_in, const int* in_sizes, int n_in,
                              void* d_out, int out_size, void* d_ws, size_t ws_size,
                              hipStream_t stream) {
  (void)in_sizes; (void)n_in; (void)out_size;
  const float* hidden = (const float*)d_in[0];
  const float* wq = (const float*)d_in[1];
  const float* wk = (const float*)d_in[2];
  const float* wv = (const float*)d_in[3];
  const float* wo = (const float*)d_in[4];
  float* out = (float*)d_out;

  const int M = 2 * S_LEN;                        // 4096
  const size_t nHid  = (size_t)M * HIDDEN;        // 8388608
  const size_t nW    = (size_t)HIDDEN * HIDDEN;   // 4194304
  const size_t nWkv  = (size_t)KVD * HIDDEN;      // 1048576
  const size_t nWcat = nW + 2 * nWkv;             // 6291456  (wq|wk|wv rows)
  const int    NQKV  = HIDDEN + 2 * KVD;          // 3072
  const size_t nQKV  = (size_t)M * NQKV;          // 12582912
  const size_t nVtp  = (size_t)M * KVD;           // 2097152

  const size_t fastElems = nHid + nWcat + nW + nQKV + nHid;  // 39845888
  if (ws_size >= fastElems * sizeof(short)) {
    short* hb   = (short*)d_ws;
    short* wcat = hb + nHid;          // [3072][2048]: wq rows, wk rows, wv rows
    short* wob  = wcat + nWcat;
    short* QKV  = wob + nW;           // [4096][3072]: Q | K | V
    short* AO   = QKV + nQKV;
    short* vtp  = hb;                 // reuse hb (dead after QKV GEMM)

    CvtArgs ca;
    ca.src[0] = hidden; ca.dst[0] = hb;            ca.cnt4[0] = (int)(nHid / 4);
    ca.src[1] = wq;     ca.dst[1] = wcat;          ca.cnt4[1] = (int)(nW / 4);
    ca.src[2] = wk;     ca.dst[2] = wcat + nW;     ca.cnt4[2] = (int)(nWkv / 4);
    ca.src[3] = wv;     ca.dst[3] = wcat + nW + nWkv; ca.cnt4[3] = (int)(nWkv / 4);
    ca.src[4] = wo;     ca.dst[4] = wob;           ca.cnt4[4] = (int)(nW / 4);
    const int total4 = (int)((nHid + nWcat + nW) / 4);
    cvt_bf16<<<2048, 256, 0, stream>>>(ca, total4);

    // fused QKV projection: [4096,3072] = hb @ wcat^T
    gemm_lds<short><<<dim3(NQKV / 128, 32), 256, 0, stream>>>(hb, wcat, QKV, M, NQKV, HIDDEN);
    // V pre-transpose + perm + XOR swizzle (hb is dead now; vtp aliases it)
    vtrans<<<dim3(S_LEN / 64, N_KV, 2), 256, 0, stream>>>(QKV + HIDDEN + KVD, NQKV, vtp);
    // fused RoPE over Q(32 heads) + K(8 heads) = cols 0..2559
    const int rtot = M * 40 * 32;
    rope_kernel<40><<<(rtot + 255) / 256, 256, 0, stream>>>(QKV, NQKV, rtot);
    // attention: Q at col 0, K at col 2048 of QKV; V from vtp
    attn_kernel<3072, 3072, HIDDEN><<<dim3(S_LEN / 128, N_HEADS, 2), 256, 0, stream>>>(
        QKV, QKV + HIDDEN, vtp, AO);
    // output projection
    gemm_lds<float><<<dim3(16, 32), 256, 0, stream>>>(AO, wob, out, M, HIDDEN, HIDDEN);
  } else {
    short* Qb  = (short*)d_ws;
    short* Kb  = Qb + nHid;
    short* Vb  = Kb + nVtp;
    short* AO  = Vb + nVtp;
    short* vtp = AO + nHid;
    gemm_bt<float, short><<<dim3(16, 32), 256, 0, stream>>>(hidden, wq, Qb, M, HIDDEN, HIDDEN);
    gemm_bt<float, short><<<dim3(4, 32), 256, 0, stream>>>(hidden, wk, Kb, M, KVD, HIDDEN);
    gemm_bt<float, short><<<dim3(4, 32), 256, 0, stream>>>(hidden, wv, Vb, M, KVD, HIDDEN);
    const int rq = M * N_HEADS * 32, rk = M * N_KV * 32;
    rope_kernel<N_HEADS><<<(rq + 255) / 256, 256, 0, stream>>>(Qb, HIDDEN, rq);
    rope_kernel<N_KV><<<(rk + 255) / 256, 256, 0, stream>>>(Kb, KVD, rk);
    vtrans<<<dim3(S_LEN / 64, N_KV, 2), 256, 0, stream>>>(Vb, KVD, vtp);
    attn_kernel<HIDDEN, KVD, HIDDEN><<<dim3(S_LEN / 128, N_HEADS, 2), 256, 0, stream>>>(
        Qb, Kb, vtp, AO);
    gemm_bt<short, float><<<dim3(16, 32), 256, 0, stream>>>(AO, wo, out, M, HIDDEN, HIDDEN);
  }
}